// Round 5
// baseline (88.267 us; speedup 1.0000x reference)
//
#include <hip/hip_runtime.h>
#include <math.h>

// out[d] = s_ho*h_o[d] + s_h*h[d]; per-token scalars from 6 dot-reductions.
// Two-phase, ONE __syncthreads per block (the vmcnt(0) drain at barriers was
// the R1/R2 latency killer): phase 1 issues ALL h loads for 8 tokens up front
// (16 float4 in flight/thread), reduces, leaders write partials to LDS;
// single barrier; phase 2 streams h_o + epilogue with no barriers at all.

constexpr int D    = 2048;
constexpr int RATE = 4;
constexpr float EPS = 1e-5f;
constexpr int TPB  = 8;   // tokens per block (16384 % 8 == 0)

__device__ __forceinline__ float fast_tanh(float x) {
    // 1 - 2/(exp(2x)+1): ~1e-6 abs err, saturates correctly at +-inf
    const float e = __expf(2.0f * x);
    return 1.0f - 2.0f / (e + 1.0f);
}

__global__ __launch_bounds__(256) void hyperconn_kernel(
    const float* __restrict__ h,
    const float* __restrict__ h_o,
    const float* __restrict__ sa,    // [4][5]
    const float* __restrict__ sb,    // [4]
    const float* __restrict__ fa,    // [2048][5]
    const float* __restrict__ a_sc,  // [1]
    const float* __restrict__ fb,    // [2048]
    const float* __restrict__ b_sc,  // [1]
    const float* __restrict__ w,     // [2048]
    float* __restrict__ out)
{
    const int tid  = threadIdx.x;          // 0..255
    const int d0   = tid * 8;
    const int wave = tid >> 6;
    const size_t t0 = (size_t)blockIdx.x * TPB;

    // ---- issue ALL h loads first: 16 float4/thread in flight
    float4 hA[TPB], hB[TPB];
    #pragma unroll
    for (int i = 0; i < TPB; ++i) {
        const float* p = h + (t0 + i) * D + d0;
        hA[i] = *reinterpret_cast<const float4*>(p);
        hB[i] = *reinterpret_cast<const float4*>(p + 4);
    }

    // ---- per-block constant tables (L2-resident)
    float4 wa = *reinterpret_cast<const float4*>(w + d0);
    float4 wb = *reinterpret_cast<const float4*>(w + d0 + 4);
    const float wv[8] = {wa.x, wa.y, wa.z, wa.w, wb.x, wb.y, wb.z, wb.w};

    float fav[32];  // fa[d0+j][1..4]
    {
        float tmp[40];
        #pragma unroll
        for (int q = 0; q < 10; ++q) {
            float4 t = *reinterpret_cast<const float4*>(fa + (size_t)d0 * 5 + q * 4);
            tmp[q*4+0]=t.x; tmp[q*4+1]=t.y; tmp[q*4+2]=t.z; tmp[q*4+3]=t.w;
        }
        #pragma unroll
        for (int j = 0; j < 8; ++j)
            #pragma unroll
            for (int c = 0; c < 4; ++c)
                fav[j*4+c] = tmp[j*5 + 1 + c];
    }
    float4 fba = *reinterpret_cast<const float4*>(fb + d0);
    float4 fbb = *reinterpret_cast<const float4*>(fb + d0 + 4);
    const float fbv[8] = {fba.x, fba.y, fba.z, fba.w, fbb.x, fbb.y, fbb.z, fbb.w};

    const float a4 = a_sc[0] * (float)RATE;
    const float b4 = b_sc[0] * (float)RATE;
    float cs = 0.f;
    #pragma unroll
    for (int r = 0; r < RATE; ++r)
        #pragma unroll
        for (int c = 1; c <= RATE; ++c)
            cs += sa[r * (RATE + 1) + c];
    const float sbsum = sb[0] + sb[1] + sb[2] + sb[3];

    // ---- phase 1: partials + wave reduce per token, leaders -> LDS
    alignas(16) __shared__ float red[TPB][24];   // [token][wave*6+k]

    #pragma unroll
    for (int i = 0; i < TPB; ++i) {
        const float hv[8] = {hA[i].x, hA[i].y, hA[i].z, hA[i].w,
                             hB[i].x, hB[i].y, hB[i].z, hB[i].w};
        float acc[6] = {0.f, 0.f, 0.f, 0.f, 0.f, 0.f};
        #pragma unroll
        for (int j = 0; j < 8; ++j) {
            const float x  = hv[j];
            const float xw = x * wv[j];
            acc[0] = fmaf(x,  x,          acc[0]);
            acc[1] = fmaf(xw, fav[j*4+0], acc[1]);
            acc[2] = fmaf(xw, fav[j*4+1], acc[2]);
            acc[3] = fmaf(xw, fav[j*4+2], acc[3]);
            acc[4] = fmaf(xw, fav[j*4+3], acc[4]);
            acc[5] = fmaf(xw, fbv[j],     acc[5]);
        }
        #pragma unroll
        for (int off = 32; off > 0; off >>= 1)
            #pragma unroll
            for (int k = 0; k < 6; ++k) acc[k] += __shfl_down(acc[k], off);
        if ((tid & 63) == 0) {
            #pragma unroll
            for (int k = 0; k < 6; ++k) red[i][wave * 6 + k] = acc[k];
        }
    }

    __syncthreads();   // the ONE barrier (and the one vmcnt drain)

    // ---- phase 2: h_o stream + scalars + fused epilogue, barrier-free
    #pragma unroll
    for (int i = 0; i < TPB; ++i) {
        const size_t base = (t0 + i) * D + d0;
        const float4 oa = *reinterpret_cast<const float4*>(h_o + base);
        const float4 ob = *reinterpret_cast<const float4*>(h_o + base + 4);

        // uniform broadcast reads of the 24 partials (6x ds_read_b128)
        const float4 f0 = *reinterpret_cast<const float4*>(&red[i][0]);
        const float4 f1 = *reinterpret_cast<const float4*>(&red[i][4]);
        const float4 f2 = *reinterpret_cast<const float4*>(&red[i][8]);
        const float4 f3 = *reinterpret_cast<const float4*>(&red[i][12]);
        const float4 f4 = *reinterpret_cast<const float4*>(&red[i][16]);
        const float4 f5 = *reinterpret_cast<const float4*>(&red[i][20]);
        const float tot0 = f0.x + f1.z + f3.x + f4.z;  // k, k+6, k+12, k+18
        const float tot1 = f0.y + f1.w + f3.y + f4.w;
        const float tot2 = f0.z + f2.x + f3.z + f5.x;
        const float tot3 = f0.w + f2.y + f3.w + f5.y;
        const float tot4 = f1.x + f2.z + f4.x + f5.z;
        const float tot5 = f1.y + f2.w + f4.y + f5.w;

        const float rms  = rsqrtf(tot0 * (1.0f / (float)D) + EPS);
        const float s_h  = a4 * (fast_tanh(tot1 * rms) + fast_tanh(tot2 * rms) +
                                 fast_tanh(tot3 * rms) + fast_tanh(tot4 * rms)) + cs;
        const float s_ho = b4 * fast_tanh(tot5 * rms) + sbsum;

        float4 r0, r1;
        r0.x = fmaf(s_ho, oa.x, s_h * hA[i].x);
        r0.y = fmaf(s_ho, oa.y, s_h * hA[i].y);
        r0.z = fmaf(s_ho, oa.z, s_h * hA[i].z);
        r0.w = fmaf(s_ho, oa.w, s_h * hA[i].w);
        r1.x = fmaf(s_ho, ob.x, s_h * hB[i].x);
        r1.y = fmaf(s_ho, ob.y, s_h * hB[i].y);
        r1.z = fmaf(s_ho, ob.z, s_h * hB[i].z);
        r1.w = fmaf(s_ho, ob.w, s_h * hB[i].w);
        *reinterpret_cast<float4*>(out + base)     = r0;
        *reinterpret_cast<float4*>(out + base + 4) = r1;
    }
}

extern "C" void kernel_launch(void* const* d_in, const int* in_sizes, int n_in,
                              void* d_out, int out_size, void* d_ws, size_t ws_size,
                              hipStream_t stream) {
    const float* h    = (const float*)d_in[0];
    const float* h_o  = (const float*)d_in[1];
    const float* sa   = (const float*)d_in[2];
    const float* sb   = (const float*)d_in[3];
    const float* fa   = (const float*)d_in[4];
    const float* a_sc = (const float*)d_in[5];
    const float* fb   = (const float*)d_in[6];
    const float* b_sc = (const float*)d_in[7];
    const float* w    = (const float*)d_in[8];
    float* out = (float*)d_out;

    const int ntok   = in_sizes[0] / D;       // B*L = 16384
    const int blocks = ntok / TPB;            // 2048
    hyperconn_kernel<<<blocks, 256, 0, stream>>>(h, h_o, sa, sb, fa, a_sc, fb, b_sc, w, out);
}

// Round 6
// 85.490 us; speedup vs baseline: 1.0325x; 1.0325x over previous
//
#include <hip/hip_runtime.h>
#include <math.h>

// out[d] = s_ho*h_o[d] + s_h*h[d]; per-token scalars from 6 dot-reductions.
// Two-phase, ONE __syncthreads per block (the vmcnt(0) drain at barriers was
// the R1/R2 latency killer): phase 1 issues ALL h loads for 8 tokens up front
// (16 float4 in flight/thread), reduces, leaders write partials to LDS;
// single barrier; phase 2 streams h_o + epilogue with no barriers at all.

constexpr int D    = 2048;
constexpr int RATE = 4;
constexpr float EPS = 1e-5f;
constexpr int TPB  = 8;   // tokens per block (16384 % 8 == 0)

__device__ __forceinline__ float fast_tanh(float x) {
    // 1 - 2/(exp(2x)+1): ~1e-6 abs err, saturates correctly at +-inf
    const float e = __expf(2.0f * x);
    return 1.0f - 2.0f / (e + 1.0f);
}

__global__ __launch_bounds__(256) void hyperconn_kernel(
    const float* __restrict__ h,
    const float* __restrict__ h_o,
    const float* __restrict__ sa,    // [4][5]
    const float* __restrict__ sb,    // [4]
    const float* __restrict__ fa,    // [2048][5]
    const float* __restrict__ a_sc,  // [1]
    const float* __restrict__ fb,    // [2048]
    const float* __restrict__ b_sc,  // [1]
    const float* __restrict__ w,     // [2048]
    float* __restrict__ out)
{
    const int tid  = threadIdx.x;          // 0..255
    const int d0   = tid * 8;
    const int wave = tid >> 6;
    const size_t t0 = (size_t)blockIdx.x * TPB;

    // ---- issue ALL h loads first: 16 float4/thread in flight
    float4 hA[TPB], hB[TPB];
    #pragma unroll
    for (int i = 0; i < TPB; ++i) {
        const float* p = h + (t0 + i) * D + d0;
        hA[i] = *reinterpret_cast<const float4*>(p);
        hB[i] = *reinterpret_cast<const float4*>(p + 4);
    }

    // ---- per-block constant tables (L2-resident)
    float4 wa = *reinterpret_cast<const float4*>(w + d0);
    float4 wb = *reinterpret_cast<const float4*>(w + d0 + 4);
    const float wv[8] = {wa.x, wa.y, wa.z, wa.w, wb.x, wb.y, wb.z, wb.w};

    float fav[32];  // fa[d0+j][1..4]
    {
        float tmp[40];
        #pragma unroll
        for (int q = 0; q < 10; ++q) {
            float4 t = *reinterpret_cast<const float4*>(fa + (size_t)d0 * 5 + q * 4);
            tmp[q*4+0]=t.x; tmp[q*4+1]=t.y; tmp[q*4+2]=t.z; tmp[q*4+3]=t.w;
        }
        #pragma unroll
        for (int j = 0; j < 8; ++j)
            #pragma unroll
            for (int c = 0; c < 4; ++c)
                fav[j*4+c] = tmp[j*5 + 1 + c];
    }
    float4 fba = *reinterpret_cast<const float4*>(fb + d0);
    float4 fbb = *reinterpret_cast<const float4*>(fb + d0 + 4);
    const float fbv[8] = {fba.x, fba.y, fba.z, fba.w, fbb.x, fbb.y, fbb.z, fbb.w};

    const float a4 = a_sc[0] * (float)RATE;
    const float b4 = b_sc[0] * (float)RATE;
    float cs = 0.f;
    #pragma unroll
    for (int r = 0; r < RATE; ++r)
        #pragma unroll
        for (int c = 1; c <= RATE; ++c)
            cs += sa[r * (RATE + 1) + c];
    const float sbsum = sb[0] + sb[1] + sb[2] + sb[3];

    // ---- phase 1: partials + wave reduce per token, leaders -> LDS
    alignas(16) __shared__ float red[TPB][24];   // [token][wave*6+k]

    #pragma unroll
    for (int i = 0; i < TPB; ++i) {
        const float hv[8] = {hA[i].x, hA[i].y, hA[i].z, hA[i].w,
                             hB[i].x, hB[i].y, hB[i].z, hB[i].w};
        float acc[6] = {0.f, 0.f, 0.f, 0.f, 0.f, 0.f};
        #pragma unroll
        for (int j = 0; j < 8; ++j) {
            const float x  = hv[j];
            const float xw = x * wv[j];
            acc[0] = fmaf(x,  x,          acc[0]);
            acc[1] = fmaf(xw, fav[j*4+0], acc[1]);
            acc[2] = fmaf(xw, fav[j*4+1], acc[2]);
            acc[3] = fmaf(xw, fav[j*4+2], acc[3]);
            acc[4] = fmaf(xw, fav[j*4+3], acc[4]);
            acc[5] = fmaf(xw, fbv[j],     acc[5]);
        }
        #pragma unroll
        for (int off = 32; off > 0; off >>= 1)
            #pragma unroll
            for (int k = 0; k < 6; ++k) acc[k] += __shfl_down(acc[k], off);
        if ((tid & 63) == 0) {
            #pragma unroll
            for (int k = 0; k < 6; ++k) red[i][wave * 6 + k] = acc[k];
        }
    }

    __syncthreads();   // the ONE barrier (and the one vmcnt drain)

    // ---- phase 2: h_o stream + scalars + fused epilogue, barrier-free
    #pragma unroll
    for (int i = 0; i < TPB; ++i) {
        const size_t base = (t0 + i) * D + d0;
        const float4 oa = *reinterpret_cast<const float4*>(h_o + base);
        const float4 ob = *reinterpret_cast<const float4*>(h_o + base + 4);

        // uniform broadcast reads of the 24 partials (6x ds_read_b128)
        const float4 f0 = *reinterpret_cast<const float4*>(&red[i][0]);
        const float4 f1 = *reinterpret_cast<const float4*>(&red[i][4]);
        const float4 f2 = *reinterpret_cast<const float4*>(&red[i][8]);
        const float4 f3 = *reinterpret_cast<const float4*>(&red[i][12]);
        const float4 f4 = *reinterpret_cast<const float4*>(&red[i][16]);
        const float4 f5 = *reinterpret_cast<const float4*>(&red[i][20]);
        const float tot0 = f0.x + f1.z + f3.x + f4.z;  // k, k+6, k+12, k+18
        const float tot1 = f0.y + f1.w + f3.y + f4.w;
        const float tot2 = f0.z + f2.x + f3.z + f5.x;
        const float tot3 = f0.w + f2.y + f3.w + f5.y;
        const float tot4 = f1.x + f2.z + f4.x + f5.z;
        const float tot5 = f1.y + f2.w + f4.y + f5.w;

        const float rms  = rsqrtf(tot0 * (1.0f / (float)D) + EPS);
        const float s_h  = a4 * (fast_tanh(tot1 * rms) + fast_tanh(tot2 * rms) +
                                 fast_tanh(tot3 * rms) + fast_tanh(tot4 * rms)) + cs;
        const float s_ho = b4 * fast_tanh(tot5 * rms) + sbsum;

        float4 r0, r1;
        r0.x = fmaf(s_ho, oa.x, s_h * hA[i].x);
        r0.y = fmaf(s_ho, oa.y, s_h * hA[i].y);
        r0.z = fmaf(s_ho, oa.z, s_h * hA[i].z);
        r0.w = fmaf(s_ho, oa.w, s_h * hA[i].w);
        r1.x = fmaf(s_ho, ob.x, s_h * hB[i].x);
        r1.y = fmaf(s_ho, ob.y, s_h * hB[i].y);
        r1.z = fmaf(s_ho, ob.z, s_h * hB[i].z);
        r1.w = fmaf(s_ho, ob.w, s_h * hB[i].w);
        *reinterpret_cast<float4*>(out + base)     = r0;
        *reinterpret_cast<float4*>(out + base + 4) = r1;
    }
}

extern "C" void kernel_launch(void* const* d_in, const int* in_sizes, int n_in,
                              void* d_out, int out_size, void* d_ws, size_t ws_size,
                              hipStream_t stream) {
    const float* h    = (const float*)d_in[0];
    const float* h_o  = (const float*)d_in[1];
    const float* sa   = (const float*)d_in[2];
    const float* sb   = (const float*)d_in[3];
    const float* fa   = (const float*)d_in[4];
    const float* a_sc = (const float*)d_in[5];
    const float* fb   = (const float*)d_in[6];
    const float* b_sc = (const float*)d_in[7];
    const float* w    = (const float*)d_in[8];
    float* out = (float*)d_out;

    const int ntok   = in_sizes[0] / D;       // B*L = 16384
    const int blocks = ntok / TPB;            // 2048
    hyperconn_kernel<<<blocks, 256, 0, stream>>>(h, h_o, sa, sb, fa, a_sc, fb, b_sc, w, out);
}

// Round 7
// 85.477 us; speedup vs baseline: 1.0326x; 1.0002x over previous
//
#include <hip/hip_runtime.h>
#include <math.h>

// out[d] = s_ho*h_o[d] + s_h*h[d]; per-token scalars from 6 dot-reductions.
// Two-phase, ONE __syncthreads per block (the vmcnt(0) drain at barriers was
// the R1/R2 latency killer): phase 1 issues ALL h loads for 8 tokens up front
// (16 float4 in flight/thread), reduces, leaders write partials to LDS;
// single barrier; phase 2 streams h_o + epilogue with no barriers at all.

constexpr int D    = 2048;
constexpr int RATE = 4;
constexpr float EPS = 1e-5f;
constexpr int TPB  = 8;   // tokens per block (16384 % 8 == 0)

__device__ __forceinline__ float fast_tanh(float x) {
    // 1 - 2/(exp(2x)+1): ~1e-6 abs err, saturates correctly at +-inf
    const float e = __expf(2.0f * x);
    return 1.0f - 2.0f / (e + 1.0f);
}

__global__ __launch_bounds__(256) void hyperconn_kernel(
    const float* __restrict__ h,
    const float* __restrict__ h_o,
    const float* __restrict__ sa,    // [4][5]
    const float* __restrict__ sb,    // [4]
    const float* __restrict__ fa,    // [2048][5]
    const float* __restrict__ a_sc,  // [1]
    const float* __restrict__ fb,    // [2048]
    const float* __restrict__ b_sc,  // [1]
    const float* __restrict__ w,     // [2048]
    float* __restrict__ out)
{
    const int tid  = threadIdx.x;          // 0..255
    const int d0   = tid * 8;
    const int wave = tid >> 6;
    const size_t t0 = (size_t)blockIdx.x * TPB;

    // ---- issue ALL h loads first: 16 float4/thread in flight
    float4 hA[TPB], hB[TPB];
    #pragma unroll
    for (int i = 0; i < TPB; ++i) {
        const float* p = h + (t0 + i) * D + d0;
        hA[i] = *reinterpret_cast<const float4*>(p);
        hB[i] = *reinterpret_cast<const float4*>(p + 4);
    }

    // ---- per-block constant tables (L2-resident)
    float4 wa = *reinterpret_cast<const float4*>(w + d0);
    float4 wb = *reinterpret_cast<const float4*>(w + d0 + 4);
    const float wv[8] = {wa.x, wa.y, wa.z, wa.w, wb.x, wb.y, wb.z, wb.w};

    float fav[32];  // fa[d0+j][1..4]
    {
        float tmp[40];
        #pragma unroll
        for (int q = 0; q < 10; ++q) {
            float4 t = *reinterpret_cast<const float4*>(fa + (size_t)d0 * 5 + q * 4);
            tmp[q*4+0]=t.x; tmp[q*4+1]=t.y; tmp[q*4+2]=t.z; tmp[q*4+3]=t.w;
        }
        #pragma unroll
        for (int j = 0; j < 8; ++j)
            #pragma unroll
            for (int c = 0; c < 4; ++c)
                fav[j*4+c] = tmp[j*5 + 1 + c];
    }
    float4 fba = *reinterpret_cast<const float4*>(fb + d0);
    float4 fbb = *reinterpret_cast<const float4*>(fb + d0 + 4);
    const float fbv[8] = {fba.x, fba.y, fba.z, fba.w, fbb.x, fbb.y, fbb.z, fbb.w};

    const float a4 = a_sc[0] * (float)RATE;
    const float b4 = b_sc[0] * (float)RATE;
    float cs = 0.f;
    #pragma unroll
    for (int r = 0; r < RATE; ++r)
        #pragma unroll
        for (int c = 1; c <= RATE; ++c)
            cs += sa[r * (RATE + 1) + c];
    const float sbsum = sb[0] + sb[1] + sb[2] + sb[3];

    // ---- phase 1: partials + wave reduce per token, leaders -> LDS
    alignas(16) __shared__ float red[TPB][24];   // [token][wave*6+k]

    #pragma unroll
    for (int i = 0; i < TPB; ++i) {
        const float hv[8] = {hA[i].x, hA[i].y, hA[i].z, hA[i].w,
                             hB[i].x, hB[i].y, hB[i].z, hB[i].w};
        float acc[6] = {0.f, 0.f, 0.f, 0.f, 0.f, 0.f};
        #pragma unroll
        for (int j = 0; j < 8; ++j) {
            const float x  = hv[j];
            const float xw = x * wv[j];
            acc[0] = fmaf(x,  x,          acc[0]);
            acc[1] = fmaf(xw, fav[j*4+0], acc[1]);
            acc[2] = fmaf(xw, fav[j*4+1], acc[2]);
            acc[3] = fmaf(xw, fav[j*4+2], acc[3]);
            acc[4] = fmaf(xw, fav[j*4+3], acc[4]);
            acc[5] = fmaf(xw, fbv[j],     acc[5]);
        }
        #pragma unroll
        for (int off = 32; off > 0; off >>= 1)
            #pragma unroll
            for (int k = 0; k < 6; ++k) acc[k] += __shfl_down(acc[k], off);
        if ((tid & 63) == 0) {
            #pragma unroll
            for (int k = 0; k < 6; ++k) red[i][wave * 6 + k] = acc[k];
        }
    }

    __syncthreads();   // the ONE barrier (and the one vmcnt drain)

    // ---- phase 2: h_o stream + scalars + fused epilogue, barrier-free
    #pragma unroll
    for (int i = 0; i < TPB; ++i) {
        const size_t base = (t0 + i) * D + d0;
        const float4 oa = *reinterpret_cast<const float4*>(h_o + base);
        const float4 ob = *reinterpret_cast<const float4*>(h_o + base + 4);

        // uniform broadcast reads of the 24 partials (6x ds_read_b128)
        const float4 f0 = *reinterpret_cast<const float4*>(&red[i][0]);
        const float4 f1 = *reinterpret_cast<const float4*>(&red[i][4]);
        const float4 f2 = *reinterpret_cast<const float4*>(&red[i][8]);
        const float4 f3 = *reinterpret_cast<const float4*>(&red[i][12]);
        const float4 f4 = *reinterpret_cast<const float4*>(&red[i][16]);
        const float4 f5 = *reinterpret_cast<const float4*>(&red[i][20]);
        const float tot0 = f0.x + f1.z + f3.x + f4.z;  // k, k+6, k+12, k+18
        const float tot1 = f0.y + f1.w + f3.y + f4.w;
        const float tot2 = f0.z + f2.x + f3.z + f5.x;
        const float tot3 = f0.w + f2.y + f3.w + f5.y;
        const float tot4 = f1.x + f2.z + f4.x + f5.z;
        const float tot5 = f1.y + f2.w + f4.y + f5.w;

        const float rms  = rsqrtf(tot0 * (1.0f / (float)D) + EPS);
        const float s_h  = a4 * (fast_tanh(tot1 * rms) + fast_tanh(tot2 * rms) +
                                 fast_tanh(tot3 * rms) + fast_tanh(tot4 * rms)) + cs;
        const float s_ho = b4 * fast_tanh(tot5 * rms) + sbsum;

        float4 r0, r1;
        r0.x = fmaf(s_ho, oa.x, s_h * hA[i].x);
        r0.y = fmaf(s_ho, oa.y, s_h * hA[i].y);
        r0.z = fmaf(s_ho, oa.z, s_h * hA[i].z);
        r0.w = fmaf(s_ho, oa.w, s_h * hA[i].w);
        r1.x = fmaf(s_ho, ob.x, s_h * hB[i].x);
        r1.y = fmaf(s_ho, ob.y, s_h * hB[i].y);
        r1.z = fmaf(s_ho, ob.z, s_h * hB[i].z);
        r1.w = fmaf(s_ho, ob.w, s_h * hB[i].w);
        *reinterpret_cast<float4*>(out + base)     = r0;
        *reinterpret_cast<float4*>(out + base + 4) = r1;
    }
}

extern "C" void kernel_launch(void* const* d_in, const int* in_sizes, int n_in,
                              void* d_out, int out_size, void* d_ws, size_t ws_size,
                              hipStream_t stream) {
    const float* h    = (const float*)d_in[0];
    const float* h_o  = (const float*)d_in[1];
    const float* sa   = (const float*)d_in[2];
    const float* sb   = (const float*)d_in[3];
    const float* fa   = (const float*)d_in[4];
    const float* a_sc = (const float*)d_in[5];
    const float* fb   = (const float*)d_in[6];
    const float* b_sc = (const float*)d_in[7];
    const float* w    = (const float*)d_in[8];
    float* out = (float*)d_out;

    const int ntok   = in_sizes[0] / D;       // B*L = 16384
    const int blocks = ntok / TPB;            // 2048
    hyperconn_kernel<<<blocks, 256, 0, stream>>>(h, h_o, sa, sb, fa, a_sc, fb, b_sc, w, out);
}

// Round 9
// 82.695 us; speedup vs baseline: 1.0674x; 1.0336x over previous
//
#include <hip/hip_runtime.h>
#include <math.h>

// out[d] = s_ho*h_o[d] + s_h*h[d]; per-token scalars from 6 dot-reductions.
// Single-barrier, full-preload structure: ALL global reads for the block's
// 8 tokens (h AND h_o, 32 dwordx4/thread, 128KB/block) are issued up front,
// so the entire HBM latency + stream time overlaps the shuffle-reduce work.
// The one __syncthreads (vmcnt drain) then completes loads we need anyway.
// Phase 2 is pure LDS-broadcast + VALU + non-temporal stores (nt keeps the
// 134MB output stream from evicting h/h_o halves out of the 256MB L3, which
// currently serves ~50% of our reads across replays).

constexpr int D    = 2048;
constexpr int RATE = 4;
constexpr float EPS = 1e-5f;
constexpr int TPB  = 8;   // tokens per block (16384 % 8 == 0)

typedef float floatx4 __attribute__((ext_vector_type(4)));  // native vec for nt-store

__device__ __forceinline__ float fast_tanh(float x) {
    // 1 - 2/(exp(2x)+1): ~1e-6 abs err, saturates correctly at +-inf
    const float e = __expf(2.0f * x);
    return 1.0f - 2.0f / (e + 1.0f);
}

__global__ __launch_bounds__(256) void hyperconn_kernel(
    const float* __restrict__ h,
    const float* __restrict__ h_o,
    const float* __restrict__ sa,    // [4][5]
    const float* __restrict__ sb,    // [4]
    const float* __restrict__ fa,    // [2048][5]
    const float* __restrict__ a_sc,  // [1]
    const float* __restrict__ fb,    // [2048]
    const float* __restrict__ b_sc,  // [1]
    const float* __restrict__ w,     // [2048]
    float* __restrict__ out)
{
    const int tid  = threadIdx.x;          // 0..255
    const int d0   = tid * 8;
    const int wave = tid >> 6;
    const size_t t0 = (size_t)blockIdx.x * TPB;

    // ---- issue the block's ENTIRE HBM read stream first: h then h_o
    float4 hA[TPB], hB[TPB], oA[TPB], oB[TPB];
    #pragma unroll
    for (int i = 0; i < TPB; ++i) {
        const float* p = h + (t0 + i) * D + d0;
        hA[i] = *reinterpret_cast<const float4*>(p);
        hB[i] = *reinterpret_cast<const float4*>(p + 4);
    }
    #pragma unroll
    for (int i = 0; i < TPB; ++i) {
        const float* p = h_o + (t0 + i) * D + d0;
        oA[i] = *reinterpret_cast<const float4*>(p);
        oB[i] = *reinterpret_cast<const float4*>(p + 4);
    }

    // ---- per-block constant tables (L2-resident)
    float4 wa = *reinterpret_cast<const float4*>(w + d0);
    float4 wb = *reinterpret_cast<const float4*>(w + d0 + 4);
    const float wv[8] = {wa.x, wa.y, wa.z, wa.w, wb.x, wb.y, wb.z, wb.w};

    float fav[32];  // fa[d0+j][1..4]
    {
        float tmp[40];
        #pragma unroll
        for (int q = 0; q < 10; ++q) {
            float4 t = *reinterpret_cast<const float4*>(fa + (size_t)d0 * 5 + q * 4);
            tmp[q*4+0]=t.x; tmp[q*4+1]=t.y; tmp[q*4+2]=t.z; tmp[q*4+3]=t.w;
        }
        #pragma unroll
        for (int j = 0; j < 8; ++j)
            #pragma unroll
            for (int c = 0; c < 4; ++c)
                fav[j*4+c] = tmp[j*5 + 1 + c];
    }
    float4 fba = *reinterpret_cast<const float4*>(fb + d0);
    float4 fbb = *reinterpret_cast<const float4*>(fb + d0 + 4);
    const float fbv[8] = {fba.x, fba.y, fba.z, fba.w, fbb.x, fbb.y, fbb.z, fbb.w};

    const float a4 = a_sc[0] * (float)RATE;
    const float b4 = b_sc[0] * (float)RATE;
    float cs = 0.f;
    #pragma unroll
    for (int r = 0; r < RATE; ++r)
        #pragma unroll
        for (int c = 1; c <= RATE; ++c)
            cs += sa[r * (RATE + 1) + c];
    const float sbsum = sb[0] + sb[1] + sb[2] + sb[3];

    // ---- phase 1: partials + wave reduce per token, leaders -> LDS
    alignas(16) __shared__ float red[TPB][24];   // [token][wave*6+k]

    #pragma unroll
    for (int i = 0; i < TPB; ++i) {
        const float hv[8] = {hA[i].x, hA[i].y, hA[i].z, hA[i].w,
                             hB[i].x, hB[i].y, hB[i].z, hB[i].w};
        float acc[6] = {0.f, 0.f, 0.f, 0.f, 0.f, 0.f};
        #pragma unroll
        for (int j = 0; j < 8; ++j) {
            const float x  = hv[j];
            const float xw = x * wv[j];
            acc[0] = fmaf(x,  x,          acc[0]);
            acc[1] = fmaf(xw, fav[j*4+0], acc[1]);
            acc[2] = fmaf(xw, fav[j*4+1], acc[2]);
            acc[3] = fmaf(xw, fav[j*4+2], acc[3]);
            acc[4] = fmaf(xw, fav[j*4+3], acc[4]);
            acc[5] = fmaf(xw, fbv[j],     acc[5]);
        }
        #pragma unroll
        for (int off = 32; off > 0; off >>= 1)
            #pragma unroll
            for (int k = 0; k < 6; ++k) acc[k] += __shfl_down(acc[k], off);
        if ((tid & 63) == 0) {
            #pragma unroll
            for (int k = 0; k < 6; ++k) red[i][wave * 6 + k] = acc[k];
        }
    }

    __syncthreads();   // the ONE barrier; drains loads we consume right now

    // ---- phase 2: pure LDS-broadcast + VALU + nt stores (no global loads)
    #pragma unroll
    for (int i = 0; i < TPB; ++i) {
        const size_t base = (t0 + i) * D + d0;

        // uniform broadcast reads of the 24 partials (6x ds_read_b128)
        const float4 f0 = *reinterpret_cast<const float4*>(&red[i][0]);
        const float4 f1 = *reinterpret_cast<const float4*>(&red[i][4]);
        const float4 f2 = *reinterpret_cast<const float4*>(&red[i][8]);
        const float4 f3 = *reinterpret_cast<const float4*>(&red[i][12]);
        const float4 f4 = *reinterpret_cast<const float4*>(&red[i][16]);
        const float4 f5 = *reinterpret_cast<const float4*>(&red[i][20]);
        const float tot0 = f0.x + f1.z + f3.x + f4.z;  // k, k+6, k+12, k+18
        const float tot1 = f0.y + f1.w + f3.y + f4.w;
        const float tot2 = f0.z + f2.x + f3.z + f5.x;
        const float tot3 = f0.w + f2.y + f3.w + f5.y;
        const float tot4 = f1.x + f2.z + f4.x + f5.z;
        const float tot5 = f1.y + f2.w + f4.y + f5.w;

        const float rms  = rsqrtf(tot0 * (1.0f / (float)D) + EPS);
        const float s_h  = a4 * (fast_tanh(tot1 * rms) + fast_tanh(tot2 * rms) +
                                 fast_tanh(tot3 * rms) + fast_tanh(tot4 * rms)) + cs;
        const float s_ho = b4 * fast_tanh(tot5 * rms) + sbsum;

        floatx4 r0, r1;
        r0.x = fmaf(s_ho, oA[i].x, s_h * hA[i].x);
        r0.y = fmaf(s_ho, oA[i].y, s_h * hA[i].y);
        r0.z = fmaf(s_ho, oA[i].z, s_h * hA[i].z);
        r0.w = fmaf(s_ho, oA[i].w, s_h * hA[i].w);
        r1.x = fmaf(s_ho, oB[i].x, s_h * hB[i].x);
        r1.y = fmaf(s_ho, oB[i].y, s_h * hB[i].y);
        r1.z = fmaf(s_ho, oB[i].z, s_h * hB[i].z);
        r1.w = fmaf(s_ho, oB[i].w, s_h * hB[i].w);
        __builtin_nontemporal_store(r0, reinterpret_cast<floatx4*>(out + base));
        __builtin_nontemporal_store(r1, reinterpret_cast<floatx4*>(out + base + 4));
    }
}

extern "C" void kernel_launch(void* const* d_in, const int* in_sizes, int n_in,
                              void* d_out, int out_size, void* d_ws, size_t ws_size,
                              hipStream_t stream) {
    const float* h    = (const float*)d_in[0];
    const float* h_o  = (const float*)d_in[1];
    const float* sa   = (const float*)d_in[2];
    const float* sb   = (const float*)d_in[3];
    const float* fa   = (const float*)d_in[4];
    const float* a_sc = (const float*)d_in[5];
    const float* fb   = (const float*)d_in[6];
    const float* b_sc = (const float*)d_in[7];
    const float* w    = (const float*)d_in[8];
    float* out = (float*)d_out;

    const int ntok   = in_sizes[0] / D;       // B*L = 16384
    const int blocks = ntok / TPB;            // 2048
    hyperconn_kernel<<<blocks, 256, 0, stream>>>(h, h_o, sa, sb, fa, a_sc, fb, b_sc, w, out);
}

// Round 10
// 82.585 us; speedup vs baseline: 1.0688x; 1.0013x over previous
//
#include <hip/hip_runtime.h>
#include <math.h>

// out[d] = s_ho*h_o[d] + s_h*h[d]; per-token scalars from 6 dot-reductions.
// Single-barrier, full-preload structure; wave reduction done with DPP
// row_shr/row_bcast adds (pure VALU, zero DS ops) instead of __shfl_down's
// ds_bpermute (which was ~290 DS ops/thread ~= 22us of serialized LDS pipe
// per CU). Lane 63 of each wave holds the wave sum and writes one partial.

constexpr int D    = 2048;
constexpr int RATE = 4;
constexpr float EPS = 1e-5f;
constexpr int TPB  = 8;   // tokens per block (16384 % 8 == 0)

__device__ __forceinline__ float fast_tanh(float x) {
    // 1 - 2/(exp(2x)+1): ~1e-6 abs err, saturates correctly at +-inf
    const float e = __expf(2.0f * x);
    return 1.0f - 2.0f / (e + 1.0f);
}

// v_add_f32 with DPP source: x + dpp_move(x). old=0 + bound_ctrl=1 make all
// masked/invalid source lanes contribute 0 to the add.
template<int CTRL>
__device__ __forceinline__ float dpp_add(float x) {
    int m = __builtin_amdgcn_update_dpp(0, __float_as_int(x), CTRL, 0xf, 0xf, true);
    return x + __int_as_float(m);
}

// After this, lane 63 holds the 64-lane sum (rocPRIM-style GCN reduce).
__device__ __forceinline__ float wave_sum_lane63(float x) {
    x = dpp_add<0x111>(x);  // row_shr:1
    x = dpp_add<0x112>(x);  // row_shr:2
    x = dpp_add<0x114>(x);  // row_shr:4
    x = dpp_add<0x118>(x);  // row_shr:8  -> lane15 of each row16 = row sum
    x = dpp_add<0x142>(x);  // row_bcast:15 -> lane31 = sum(0..31), lane63 = sum(32..63)
    x = dpp_add<0x143>(x);  // row_bcast:31 -> lane63 = sum(0..63)
    return x;
}

__global__ __launch_bounds__(256) void hyperconn_kernel(
    const float* __restrict__ h,
    const float* __restrict__ h_o,
    const float* __restrict__ sa,    // [4][5]
    const float* __restrict__ sb,    // [4]
    const float* __restrict__ fa,    // [2048][5]
    const float* __restrict__ a_sc,  // [1]
    const float* __restrict__ fb,    // [2048]
    const float* __restrict__ b_sc,  // [1]
    const float* __restrict__ w,     // [2048]
    float* __restrict__ out)
{
    const int tid  = threadIdx.x;          // 0..255
    const int d0   = tid * 8;
    const int wave = tid >> 6;
    const size_t t0 = (size_t)blockIdx.x * TPB;

    // ---- issue the block's ENTIRE HBM read stream first: h then h_o
    float4 hA[TPB], hB[TPB], oA[TPB], oB[TPB];
    #pragma unroll
    for (int i = 0; i < TPB; ++i) {
        const float* p = h + (t0 + i) * D + d0;
        hA[i] = *reinterpret_cast<const float4*>(p);
        hB[i] = *reinterpret_cast<const float4*>(p + 4);
    }
    #pragma unroll
    for (int i = 0; i < TPB; ++i) {
        const float* p = h_o + (t0 + i) * D + d0;
        oA[i] = *reinterpret_cast<const float4*>(p);
        oB[i] = *reinterpret_cast<const float4*>(p + 4);
    }

    // ---- per-block constant tables (L2-resident)
    float4 wa = *reinterpret_cast<const float4*>(w + d0);
    float4 wb = *reinterpret_cast<const float4*>(w + d0 + 4);
    const float wv[8] = {wa.x, wa.y, wa.z, wa.w, wb.x, wb.y, wb.z, wb.w};

    float fav[32];  // fa[d0+j][1..4]
    {
        float tmp[40];
        #pragma unroll
        for (int q = 0; q < 10; ++q) {
            float4 t = *reinterpret_cast<const float4*>(fa + (size_t)d0 * 5 + q * 4);
            tmp[q*4+0]=t.x; tmp[q*4+1]=t.y; tmp[q*4+2]=t.z; tmp[q*4+3]=t.w;
        }
        #pragma unroll
        for (int j = 0; j < 8; ++j)
            #pragma unroll
            for (int c = 0; c < 4; ++c)
                fav[j*4+c] = tmp[j*5 + 1 + c];
    }
    float4 fba = *reinterpret_cast<const float4*>(fb + d0);
    float4 fbb = *reinterpret_cast<const float4*>(fb + d0 + 4);
    const float fbv[8] = {fba.x, fba.y, fba.z, fba.w, fbb.x, fbb.y, fbb.z, fbb.w};

    const float a4 = a_sc[0] * (float)RATE;
    const float b4 = b_sc[0] * (float)RATE;
    float cs = 0.f;
    #pragma unroll
    for (int r = 0; r < RATE; ++r)
        #pragma unroll
        for (int c = 1; c <= RATE; ++c)
            cs += sa[r * (RATE + 1) + c];
    const float sbsum = sb[0] + sb[1] + sb[2] + sb[3];

    // ---- phase 1: partials + DPP wave reduce per token, lane63 -> LDS
    alignas(16) __shared__ float red[TPB][24];   // [token][wave*6+k]

    #pragma unroll
    for (int i = 0; i < TPB; ++i) {
        const float hv[8] = {hA[i].x, hA[i].y, hA[i].z, hA[i].w,
                             hB[i].x, hB[i].y, hB[i].z, hB[i].w};
        float acc[6] = {0.f, 0.f, 0.f, 0.f, 0.f, 0.f};
        #pragma unroll
        for (int j = 0; j < 8; ++j) {
            const float x  = hv[j];
            const float xw = x * wv[j];
            acc[0] = fmaf(x,  x,          acc[0]);
            acc[1] = fmaf(xw, fav[j*4+0], acc[1]);
            acc[2] = fmaf(xw, fav[j*4+1], acc[2]);
            acc[3] = fmaf(xw, fav[j*4+2], acc[3]);
            acc[4] = fmaf(xw, fav[j*4+3], acc[4]);
            acc[5] = fmaf(xw, fbv[j],     acc[5]);
        }
        #pragma unroll
        for (int k = 0; k < 6; ++k) acc[k] = wave_sum_lane63(acc[k]);
        if ((tid & 63) == 63) {
            #pragma unroll
            for (int k = 0; k < 6; ++k) red[i][wave * 6 + k] = acc[k];
        }
    }

    __syncthreads();   // the ONE barrier

    // ---- phase 2: pure LDS-broadcast + VALU + stores (no global loads)
    #pragma unroll
    for (int i = 0; i < TPB; ++i) {
        const size_t base = (t0 + i) * D + d0;

        // uniform broadcast reads of the 24 partials (6x ds_read_b128)
        const float4 f0 = *reinterpret_cast<const float4*>(&red[i][0]);
        const float4 f1 = *reinterpret_cast<const float4*>(&red[i][4]);
        const float4 f2 = *reinterpret_cast<const float4*>(&red[i][8]);
        const float4 f3 = *reinterpret_cast<const float4*>(&red[i][12]);
        const float4 f4 = *reinterpret_cast<const float4*>(&red[i][16]);
        const float4 f5 = *reinterpret_cast<const float4*>(&red[i][20]);
        const float tot0 = f0.x + f1.z + f3.x + f4.z;  // k, k+6, k+12, k+18
        const float tot1 = f0.y + f1.w + f3.y + f4.w;
        const float tot2 = f0.z + f2.x + f3.z + f5.x;
        const float tot3 = f0.w + f2.y + f3.w + f5.y;
        const float tot4 = f1.x + f2.z + f4.x + f5.z;
        const float tot5 = f1.y + f2.w + f4.y + f5.w;

        const float rms  = rsqrtf(tot0 * (1.0f / (float)D) + EPS);
        const float s_h  = a4 * (fast_tanh(tot1 * rms) + fast_tanh(tot2 * rms) +
                                 fast_tanh(tot3 * rms) + fast_tanh(tot4 * rms)) + cs;
        const float s_ho = b4 * fast_tanh(tot5 * rms) + sbsum;

        float4 r0, r1;
        r0.x = fmaf(s_ho, oA[i].x, s_h * hA[i].x);
        r0.y = fmaf(s_ho, oA[i].y, s_h * hA[i].y);
        r0.z = fmaf(s_ho, oA[i].z, s_h * hA[i].z);
        r0.w = fmaf(s_ho, oA[i].w, s_h * hA[i].w);
        r1.x = fmaf(s_ho, oB[i].x, s_h * hB[i].x);
        r1.y = fmaf(s_ho, oB[i].y, s_h * hB[i].y);
        r1.z = fmaf(s_ho, oB[i].z, s_h * hB[i].z);
        r1.w = fmaf(s_ho, oB[i].w, s_h * hB[i].w);
        *reinterpret_cast<float4*>(out + base)     = r0;
        *reinterpret_cast<float4*>(out + base + 4) = r1;
    }
}

extern "C" void kernel_launch(void* const* d_in, const int* in_sizes, int n_in,
                              void* d_out, int out_size, void* d_ws, size_t ws_size,
                              hipStream_t stream) {
    const float* h    = (const float*)d_in[0];
    const float* h_o  = (const float*)d_in[1];
    const float* sa   = (const float*)d_in[2];
    const float* sb   = (const float*)d_in[3];
    const float* fa   = (const float*)d_in[4];
    const float* a_sc = (const float*)d_in[5];
    const float* fb   = (const float*)d_in[6];
    const float* b_sc = (const float*)d_in[7];
    const float* w    = (const float*)d_in[8];
    float* out = (float*)d_out;

    const int ntok   = in_sizes[0] / D;       // B*L = 16384
    const int blocks = ntok / TPB;            // 2048
    hyperconn_kernel<<<blocks, 256, 0, stream>>>(h, h_o, sa, sb, fa, a_sc, fb, b_sc, w, out);
}